// Round 9
// baseline (754.631 us; speedup 1.0000x reference)
//
#include <hip/hip_runtime.h>
#include <hip/hip_bf16.h>

#define NN 100000
#define EE 1600000
#define NBC 196          // coarse buckets of 512 nodes
#define NPB 512
#define CAPC 8960        // per-coarse capacity; mean 8163, ~8.5 sigma
#define CHA 2048         // edges per binA block
#define NBLA 782         // ceil(EE/CHA)
#define NLIN 1563        // ceil(NN/64)

// workspace byte offsets (256-aligned)
#define OFF_CCNT 0u               // NBC*4 = 784
#define OFF_DEG  1024u            // NN*4
#define OFF_NS   401024u          // NN*4
#define OFF_CBUF 801280u          // NBC*CAPC*4 = 7024640
#define OFF_CSR  7825920u         // NBC*CAPC*4
#define OFF_P    14850560u        // NN*64*2 (bf16)
#define OFF_Q    27650560u        // NN*64*2
#define OFF_WFT  40450560u        // 64*128*2 (bf16, [col][k] of [w2;ws])
// total 40466944 B ~= 38.6 MB

typedef __attribute__((ext_vector_type(8))) short bf16x8;
typedef __attribute__((ext_vector_type(4))) float f32x4;

__device__ __forceinline__ ushort f2bf(float f) {
  unsigned u = __float_as_uint(f);
  unsigned r = (u + 0x7FFFu + ((u >> 16) & 1u)) >> 16;
  return (ushort)r;
}
__device__ __forceinline__ unsigned pk2(float a, float b) {
  return (unsigned)f2bf(a) | ((unsigned)f2bf(b) << 16);
}
__device__ __forceinline__ float uplo(unsigned u) {
  return __uint_as_float(u << 16);
}
__device__ __forceinline__ float uphi(unsigned u) {
  return __uint_as_float(u & 0xFFFF0000u);
}

// ===== K1: binA (blocks < NBLA) | lin1 (next NLIN) | WfT prep (last) =========
__launch_bounds__(256)
__global__ void k_pre(const int* __restrict__ ei, int* __restrict__ ccnt,
                      unsigned* __restrict__ cbuf, const float* __restrict__ x,
                      const float* __restrict__ w1, const float* __restrict__ b1,
                      const float* __restrict__ w2, const float* __restrict__ wsw,
                      ushort* __restrict__ P, ushort* __restrict__ Qb,
                      ushort* __restrict__ WfT) {
  __shared__ alignas(16) char sm[25600];
  int t = threadIdx.x;
  unsigned bid = blockIdx.x;
  if (bid < NBLA) {
    // ---- binA: sort 2048-edge chunk into 196 coarse buckets ----
    int* hist   = (int*)sm;            // [256] (196 used)
    int* offs   = hist + 256;
    int* starts = offs + 256;
    int* gbase  = starts + 256;
    int* wtot   = gbase + 256;         // [4]
    unsigned* sorted = (unsigned*)(wtot + 8);   // [2048]
    ushort* bkt = (ushort*)(sorted + CHA);      // [2048]
    if (t < NBC) hist[t] = 0;
    __syncthreads();
    unsigned ent[8];
    int cb[8];
    int e0 = bid * CHA;
    #pragma unroll
    for (int it = 0; it < 8; ++it) {
      int e = e0 + t + it * 256;
      cb[it] = -1;
      if (e < EE) {
        int s = ei[e], d = ei[EE + e];
        ent[it] = (unsigned)s | ((unsigned)(d & 511) << 17);
        cb[it] = d >> 9;
        atomicAdd(&hist[cb[it]], 1);
      }
    }
    __syncthreads();
    {
      int v = (t < NBC) ? hist[t] : 0;
      int xv = v;
      #pragma unroll
      for (int off = 1; off < 64; off <<= 1) {
        int w = __shfl_up(xv, off);
        if ((t & 63) >= off) xv += w;
      }
      if ((t & 63) == 63) wtot[t >> 6] = xv;
      __syncthreads();
      int pre = 0;
      #pragma unroll
      for (int w = 0; w < 4; ++w)
        if (w < (t >> 6)) pre += wtot[w];
      if (t < NBC) { offs[t] = pre + xv - v; starts[t] = pre + xv - v; }
    }
    __syncthreads();
    #pragma unroll
    for (int it = 0; it < 8; ++it) {
      if (cb[it] >= 0) {
        int pos = atomicAdd(&offs[cb[it]], 1);
        sorted[pos] = ent[it];
        bkt[pos] = (ushort)cb[it];
      }
    }
    __syncthreads();
    if (t < NBC) {
      int c = hist[t];
      gbase[t] = (c > 0) ? atomicAdd(&ccnt[t], c) : 0;
    }
    __syncthreads();
    int tot = min(EE - e0, CHA);
    for (int i = t; i < tot; i += 256) {
      int b = bkt[i];
      int dst = gbase[b] + (i - starts[b]);
      if (dst < CAPC) cbuf[b * CAPC + dst] = sorted[i];
    }
    return;
  }
  if (bid < NBLA + NLIN) {
    // ---- lin1 (MFMA): P = x@w1[:64], Qb = x@w1[64:] + b1 ----
    ushort* xbf = (ushort*)sm;          // 64*72*2 = 9216
    ushort* w1t = (ushort*)(sm + 9216); // 8192*2 = 16384 (total 25600)
    int base = (bid - NBLA) * 64;
    // self-transpose w1 -> [c_ext][k] bf16 (w1 is L2-hot across blocks)
    for (int idx = t; idx < 8192; idx += 256) {
      int ce = idx >> 6, k = idx & 63;
      int col = ce & 63, half = ce >> 6;
      w1t[idx] = f2bf(w1[(half * 64 + k) * 64 + col]);
    }
    #pragma unroll
    for (int i = 0; i < 4; ++i) {
      int idx4 = t + i * 256;
      int r = idx4 >> 4, c = idx4 & 15;
      int grow = base + r;
      float4 v = make_float4(0.f, 0.f, 0.f, 0.f);
      if (grow < NN) v = reinterpret_cast<const float4*>(x)[grow * 16 + c];
      *reinterpret_cast<uint2*>(&xbf[r * 72 + c * 4]) =
          make_uint2(pk2(v.x, v.y), pk2(v.z, v.w));
    }
    __syncthreads();
    int w = t >> 6, l = t & 63;
    int li = l & 15, lg = l >> 4;
    f32x4 acc[8];
    #pragma unroll
    for (int n = 0; n < 8; ++n) acc[n] = (f32x4){0.f, 0.f, 0.f, 0.f};
    #pragma unroll
    for (int s = 0; s < 2; ++s) {
      bf16x8 a = *reinterpret_cast<const bf16x8*>(&xbf[(w * 16 + li) * 72 + s * 32 + lg * 8]);
      #pragma unroll
      for (int n = 0; n < 8; ++n) {
        bf16x8 b = *reinterpret_cast<const bf16x8*>(&w1t[(n * 16 + li) * 64 + s * 32 + lg * 8]);
        acc[n] = __builtin_amdgcn_mfma_f32_16x16x32_bf16(a, b, acc[n], 0, 0, 0);
      }
    }
    #pragma unroll
    for (int n = 0; n < 8; ++n) {
      int col = (n & 3) * 16 + li;
      ushort* dstb = (n < 4) ? P : Qb;
      float badd = (n < 4) ? 0.f : b1[col];
      #pragma unroll
      for (int q = 0; q < 4; ++q) {
        int row = base + w * 16 + lg * 4 + q;
        if (row < NN) dstb[row * 64 + col] = f2bf(acc[n][q] + badd);
      }
    }
    return;
  }
  // ---- prep: WfT[col*128 + k] = bf16 of [w2;ws][k][col] ----
  for (int idx = t; idx < 8192; idx += 256) {
    int c = idx >> 7, k = idx & 127;
    WfT[idx] = f2bf(k < 64 ? w2[k * 64 + c] : wsw[(k - 64) * 64 + c]);
  }
}

// ===== csr: per coarse bucket, 512-way counting sort -> node-sorted CSR ======
// keeps full entry (src | ldst9<<17) so k_af can recover local dst.
__launch_bounds__(512)
__global__ void k_csr(const int* __restrict__ ccnt, const unsigned* __restrict__ cbuf,
                      unsigned* __restrict__ csr, int* __restrict__ ns,
                      int* __restrict__ deg) {
  __shared__ int hist[512], offs[512], starts[512], wpre[8];
  int cb = blockIdx.x;
  int t = threadIdx.x;
  hist[t] = 0;
  __syncthreads();
  int tot = min(ccnt[cb], CAPC);
  const unsigned* cb_base = cbuf + cb * CAPC;
  for (int i = t; i < tot; i += 512)
    atomicAdd(&hist[cb_base[i] >> 17], 1);
  __syncthreads();
  int v = hist[t];
  int xv = v;
  int lane = t & 63;
  int w = t >> 6;
  #pragma unroll
  for (int off = 1; off < 64; off <<= 1) {
    int q = __shfl_up(xv, off);
    if (lane >= off) xv += q;
  }
  if (lane == 63) wpre[w] = xv;
  __syncthreads();
  if (t < 8) {
    int s = wpre[t];
    int xx = s;
    #pragma unroll
    for (int off = 1; off < 8; off <<= 1) {
      int q = __shfl_up(xx, off);
      if (t >= off) xx += q;
    }
    wpre[t] = xx - s;
  }
  __syncthreads();
  int ex = wpre[w] + xv - v;
  offs[t] = ex;
  starts[t] = ex;
  __syncthreads();
  for (int i = t; i < tot; i += 512) {
    unsigned e = cb_base[i];
    int pos = atomicAdd(&offs[e >> 17], 1);
    csr[cb * CAPC + pos] = e;  // scatter within 35KB window: L2-absorbed
  }
  int n = cb * NPB + t;
  if (n < NN) {
    ns[n] = cb * CAPC + starts[t];
    deg[n] = hist[t];
  }
}

// ===== k_af: edge-stream aggregate (LDS f32 atomics) + final MFMA ============
__launch_bounds__(256)
__global__ void k_af(const unsigned* __restrict__ csr, const int* __restrict__ ns,
                     const int* __restrict__ deg, const uint2* __restrict__ P2,
                     const uint2* __restrict__ Q2, const float* __restrict__ x,
                     const ushort* __restrict__ WfT, const float* __restrict__ b2,
                     const float* __restrict__ bs, float* __restrict__ out) {
  __shared__ alignas(16) char sm[25600];
  float* uacc = (float*)sm;                    // [64][64] f32, 16384 B (phase A)
  ushort* ubf = (ushort*)sm;                   // [64][72] bf16, 9216 B (phase B, alias)
  uint2* qbl  = (uint2*)(sm + 16384);          // [64][16] uint2, 8192 B (phase A)
  ushort* xbf = (ushort*)(sm + 16384);         // [64][72] bf16, 9216 B (phase B, alias)
  int t = threadIdx.x;
  int n0 = blockIdx.x * 64;
  // stage Qb tile + zero uacc
  #pragma unroll
  for (int i = 0; i < 4; ++i) {
    int idx = t + i * 256;
    int r = idx >> 4, c = idx & 15;
    int gn = n0 + r;
    uint2 v = make_uint2(0u, 0u);
    if (gn < NN) v = Q2[gn * 16 + c];
    qbl[idx] = v;
  }
  #pragma unroll
  for (int j = 0; j < 16; ++j) uacc[t + j * 256] = 0.f;
  int nlast = min(n0 + 63, NN - 1);
  int est = ns[n0];
  int eend = ns[nlast] + deg[nlast];
  __syncthreads();
  // phase A: stream contiguous edge range, accumulate into uacc
  int w = t >> 6, lane = t & 63;
  int eg = lane >> 4, c = lane & 15;
  for (int i = est + w * 4 + eg; i < eend; i += 16) {
    unsigned e = csr[i];
    int s = e & 0x1FFFF;
    int l6 = (e >> 17) & 63;
    uint2 p = P2[s * 16 + c];
    uint2 q = qbl[l6 * 16 + c];
    float v0 = fmaxf(uplo(p.x) + uplo(q.x), 0.f);
    float v1 = fmaxf(uphi(p.x) + uphi(q.x), 0.f);
    float v2 = fmaxf(uplo(p.y) + uplo(q.y), 0.f);
    float v3 = fmaxf(uphi(p.y) + uphi(q.y), 0.f);
    float* ur = &uacc[l6 * 64 + c * 4];
    atomicAdd(ur + 0, v0);
    atomicAdd(ur + 1, v1);
    atomicAdd(ur + 2, v2);
    atomicAdd(ur + 3, v3);
  }
  __syncthreads();
  // transition: uacc -> regs (mean), issue x loads, then write bf16 tiles
  int r = t >> 2;
  int c0 = (t & 3) * 16;
  int gn = n0 + r;
  int dg = (gn < NN) ? deg[gn] : 0;
  float inv = 1.f / (float)max(dg, 1);
  float uv[16];
  #pragma unroll
  for (int j = 0; j < 16; ++j) uv[j] = uacc[r * 64 + c0 + j] * inv;
  float4 xr[4];
  #pragma unroll
  for (int i = 0; i < 4; ++i) {
    int idx = t + i * 256;
    int rr = idx >> 4, cc = idx & 15;
    int g2 = n0 + rr;
    xr[i] = (g2 < NN) ? reinterpret_cast<const float4*>(x)[g2 * 16 + cc]
                      : make_float4(0.f, 0.f, 0.f, 0.f);
  }
  __syncthreads();  // all uacc reads done before ubf overwrite
  #pragma unroll
  for (int j = 0; j < 16; j += 2)
    *reinterpret_cast<unsigned*>(&ubf[r * 72 + c0 + j]) = pk2(uv[j], uv[j + 1]);
  #pragma unroll
  for (int i = 0; i < 4; ++i) {
    int idx = t + i * 256;
    int rr = idx >> 4, cc = idx & 15;
    *reinterpret_cast<uint2*>(&xbf[rr * 72 + cc * 4]) =
        make_uint2(pk2(xr[i].x, xr[i].y), pk2(xr[i].z, xr[i].w));
  }
  __syncthreads();
  // phase B: out = [u,x] @ WfT^T + bs (+ b2 iff deg>0)
  int li = lane & 15, lg = lane >> 4;
  f32x4 acc[4];
  #pragma unroll
  for (int n = 0; n < 4; ++n) acc[n] = (f32x4){0.f, 0.f, 0.f, 0.f};
  #pragma unroll
  for (int s = 0; s < 4; ++s) {
    const ushort* src = (s < 2) ? ubf : xbf;
    bf16x8 a = *reinterpret_cast<const bf16x8*>(&src[(w * 16 + li) * 72 + (s & 1) * 32 + lg * 8]);
    #pragma unroll
    for (int n = 0; n < 4; ++n) {
      bf16x8 b = *reinterpret_cast<const bf16x8*>(&WfT[(n * 16 + li) * 128 + s * 32 + lg * 8]);
      acc[n] = __builtin_amdgcn_mfma_f32_16x16x32_bf16(a, b, acc[n], 0, 0, 0);
    }
  }
  #pragma unroll
  for (int n = 0; n < 4; ++n) {
    int col = n * 16 + li;
    float bsv = bs[col], b2v = b2[col];
    #pragma unroll
    for (int q = 0; q < 4; ++q) {
      int row = n0 + w * 16 + lg * 4 + q;
      if (row < NN) {
        float add = (deg[row] > 0) ? b2v : 0.f;
        out[row * 64 + col] = acc[n][q] + bsv + add;
      }
    }
  }
}

extern "C" void kernel_launch(void* const* d_in, const int* in_sizes, int n_in,
                              void* d_out, int out_size, void* d_ws, size_t ws_size,
                              hipStream_t stream) {
  const float* x   = (const float*)d_in[0];
  const int*   ei  = (const int*)d_in[1];
  const float* w1  = (const float*)d_in[2];
  const float* b1  = (const float*)d_in[3];
  const float* w2  = (const float*)d_in[4];
  const float* b2  = (const float*)d_in[5];
  const float* wsw = (const float*)d_in[6];
  const float* bs  = (const float*)d_in[7];
  float* out = (float*)d_out;
  char* ws = (char*)d_ws;
  int* ccnt      = (int*)(ws + OFF_CCNT);
  int* deg       = (int*)(ws + OFF_DEG);
  int* ns        = (int*)(ws + OFF_NS);
  unsigned* cbuf = (unsigned*)(ws + OFF_CBUF);
  unsigned* csr  = (unsigned*)(ws + OFF_CSR);
  ushort* P      = (ushort*)(ws + OFF_P);
  ushort* Qb     = (ushort*)(ws + OFF_Q);
  ushort* WfT    = (ushort*)(ws + OFF_WFT);

  hipMemsetAsync(ccnt, 0, NBC * sizeof(int), stream);
  k_pre<<<NBLA + NLIN + 1, 256, 0, stream>>>(ei, ccnt, cbuf, x, w1, b1, w2, wsw,
                                             P, Qb, WfT);
  k_csr<<<NBC, 512, 0, stream>>>(ccnt, cbuf, csr, ns, deg);
  k_af<<<NLIN, 256, 0, stream>>>(csr, ns, deg, (const uint2*)P, (const uint2*)Qb,
                                 x, WfT, b2, bs, out);
}

// Round 10
// 206.626 us; speedup vs baseline: 3.6522x; 3.6522x over previous
//
#include <hip/hip_runtime.h>
#include <hip/hip_bf16.h>

#define NN 100000
#define EE 1600000
#define NBC 391          // coarse buckets of 256 nodes
#define NPB 256
#define CAPC 4608        // per-coarse capacity; mean 4094, ~8 sigma
#define CHA 2048         // edges per binA block
#define NBLA 782         // ceil(EE/CHA)
#define NLI1 782         // lin1 tiles of 128 nodes
#define NAF 6250         // aggfinal blocks of 16 nodes (exact: 6250*16=100000)

// workspace byte offsets (256-aligned)
#define OFF_CCNT 0u               // 391*4 = 1564
#define OFF_DEG  2048u            // NN*4
#define OFF_NS   402176u          // NN*4
#define OFF_CBUF 802304u          // NBC*CAPC*4 = 7206912
#define OFF_CSR  8009216u        // NBC*CAPC*4
#define OFF_P    15216128u       // NN*64*2 (bf16)
#define OFF_Q    28016128u       // NN*64*2
#define OFF_WFT  40816128u       // 64*128*2 (bf16, [col][k] of [w2;ws])
// total 40832512 B ~= 38.9 MB

typedef __attribute__((ext_vector_type(8))) short bf16x8;
typedef __attribute__((ext_vector_type(4))) float f32x4;

__device__ __forceinline__ ushort f2bf(float f) {
  unsigned u = __float_as_uint(f);
  unsigned r = (u + 0x7FFFu + ((u >> 16) & 1u)) >> 16;
  return (ushort)r;
}
__device__ __forceinline__ unsigned pk2(float a, float b) {
  return (unsigned)f2bf(a) | ((unsigned)f2bf(b) << 16);
}
__device__ __forceinline__ float uplo(unsigned u) {
  return __uint_as_float(u << 16);
}
__device__ __forceinline__ float uphi(unsigned u) {
  return __uint_as_float(u & 0xFFFF0000u);
}

// ===== k_pre: binA (blocks<NBLA) | lin1-MFMA (next NLI1) | WfT prep (last) ===
__launch_bounds__(512)
__global__ void k_pre(const int* __restrict__ ei, int* __restrict__ ccnt,
                      unsigned* __restrict__ cbuf, const float* __restrict__ x,
                      const float* __restrict__ w1, const float* __restrict__ b1,
                      const float* __restrict__ w2, const float* __restrict__ wsw,
                      ushort* __restrict__ P, ushort* __restrict__ Qb,
                      ushort* __restrict__ WfT) {
  __shared__ alignas(16) char sm[34816];
  int t = threadIdx.x;
  unsigned bid = blockIdx.x;
  if (bid < NBLA) {
    // ---- binA: sort 2048-edge chunk into 391 coarse buckets ----
    int* hist   = (int*)sm;             // [392]
    int* offs   = hist + 392;
    int* starts = offs + 392;
    int* gbase  = starts + 392;
    int* wtot   = gbase + 392;          // [8]
    unsigned* sorted = (unsigned*)(wtot + 8);   // [2048]
    ushort* bkt = (ushort*)(sorted + CHA);      // [2048]
    if (t < NBC) hist[t] = 0;
    __syncthreads();
    unsigned ent[4];
    int cb[4];
    int e0 = bid * CHA;
    #pragma unroll
    for (int it = 0; it < 4; ++it) {
      int e = e0 + t + it * 512;
      cb[it] = -1;
      if (e < EE) {
        int s = ei[e], d = ei[EE + e];
        ent[it] = (unsigned)s | ((unsigned)(d & 255) << 17);
        cb[it] = d >> 8;
        atomicAdd(&hist[cb[it]], 1);
      }
    }
    __syncthreads();
    {
      int v = (t < NBC) ? hist[t] : 0;
      int xv = v;
      #pragma unroll
      for (int off = 1; off < 64; off <<= 1) {
        int w = __shfl_up(xv, off);
        if ((t & 63) >= off) xv += w;
      }
      if ((t & 63) == 63) wtot[t >> 6] = xv;
      __syncthreads();
      int pre = 0;
      #pragma unroll
      for (int w = 0; w < 8; ++w)
        if (w < (t >> 6)) pre += wtot[w];
      if (t < NBC) { offs[t] = pre + xv - v; starts[t] = pre + xv - v; }
    }
    __syncthreads();
    #pragma unroll
    for (int it = 0; it < 4; ++it) {
      if (cb[it] >= 0) {
        int pos = atomicAdd(&offs[cb[it]], 1);
        sorted[pos] = ent[it];
        bkt[pos] = (ushort)cb[it];
      }
    }
    __syncthreads();
    if (t < NBC) {
      int c = hist[t];
      gbase[t] = (c > 0) ? atomicAdd(&ccnt[t], c) : 0;
    }
    __syncthreads();
    int tot = min(EE - e0, CHA);
    for (int i = t; i < tot; i += 512) {
      int b = bkt[i];
      int dst = gbase[b] + (i - starts[b]);
      if (dst < CAPC) cbuf[b * CAPC + dst] = sorted[i];
    }
    return;
  }
  if (bid < NBLA + NLI1) {
    // ---- lin1 (MFMA, 128-row tile): P = x@w1[:64], Qb = x@w1[64:] + b1 ----
    ushort* xbf = (ushort*)sm;           // 128*72*2 = 18432
    ushort* w1t = (ushort*)(sm + 18432); // 8192*2 = 16384
    int base = (bid - NBLA) * 128;
    for (int idx = t; idx < 8192; idx += 512) {
      int ce = idx >> 6, k = idx & 63;
      int col = ce & 63, half = ce >> 6;
      w1t[idx] = f2bf(w1[(half * 64 + k) * 64 + col]);
    }
    #pragma unroll
    for (int i = 0; i < 4; ++i) {
      int idx = t + i * 512;
      int r = idx >> 4, c = idx & 15;
      int grow = base + r;
      float4 v = make_float4(0.f, 0.f, 0.f, 0.f);
      if (grow < NN) v = reinterpret_cast<const float4*>(x)[grow * 16 + c];
      *reinterpret_cast<uint2*>(&xbf[r * 72 + c * 4]) =
          make_uint2(pk2(v.x, v.y), pk2(v.z, v.w));
    }
    __syncthreads();
    int w = t >> 6, l = t & 63;
    int li = l & 15, lg = l >> 4;
    f32x4 acc[8];
    #pragma unroll
    for (int n = 0; n < 8; ++n) acc[n] = (f32x4){0.f, 0.f, 0.f, 0.f};
    #pragma unroll
    for (int s = 0; s < 2; ++s) {
      bf16x8 a = *reinterpret_cast<const bf16x8*>(&xbf[(w * 16 + li) * 72 + s * 32 + lg * 8]);
      #pragma unroll
      for (int n = 0; n < 8; ++n) {
        bf16x8 b = *reinterpret_cast<const bf16x8*>(&w1t[(n * 16 + li) * 64 + s * 32 + lg * 8]);
        acc[n] = __builtin_amdgcn_mfma_f32_16x16x32_bf16(a, b, acc[n], 0, 0, 0);
      }
    }
    #pragma unroll
    for (int n = 0; n < 8; ++n) {
      int col = (n & 3) * 16 + li;
      ushort* dstb = (n < 4) ? P : Qb;
      float badd = (n < 4) ? 0.f : b1[col];
      #pragma unroll
      for (int q = 0; q < 4; ++q) {
        int row = base + w * 16 + lg * 4 + q;
        if (row < NN) dstb[row * 64 + col] = f2bf(acc[n][q] + badd);
      }
    }
    return;
  }
  // ---- WfT[col*128 + k] = bf16 of [w2;ws][k][col] ----
  for (int idx = t; idx < 8192; idx += 512) {
    int c = idx >> 7, k = idx & 127;
    WfT[idx] = f2bf(k < 64 ? w2[k * 64 + c] : wsw[(k - 64) * 64 + c]);
  }
}

// ===== k_csr: per coarse bucket (256 nodes), counting sort -> node CSR =======
__launch_bounds__(256)
__global__ void k_csr(const int* __restrict__ ccnt, const unsigned* __restrict__ cbuf,
                      unsigned* __restrict__ csr, int* __restrict__ ns,
                      int* __restrict__ deg) {
  __shared__ int hist[256], offs[256], starts[256], wpre[4];
  int cb = blockIdx.x;
  int t = threadIdx.x;
  hist[t] = 0;
  __syncthreads();
  int tot = min(ccnt[cb], CAPC);
  const unsigned* cb_base = cbuf + cb * CAPC;
  for (int i = t; i < tot; i += 256)
    atomicAdd(&hist[(cb_base[i] >> 17) & 255], 1);
  __syncthreads();
  int v = hist[t];
  int xv = v;
  int lane = t & 63;
  int w = t >> 6;
  #pragma unroll
  for (int off = 1; off < 64; off <<= 1) {
    int q = __shfl_up(xv, off);
    if (lane >= off) xv += q;
  }
  if (lane == 63) wpre[w] = xv;
  __syncthreads();
  if (t < 4) {
    int s = wpre[t];
    int xx = s;
    #pragma unroll
    for (int off = 1; off < 4; off <<= 1) {
      int q = __shfl_up(xx, off);
      if (t >= off) xx += q;
    }
    wpre[t] = xx - s;
  }
  __syncthreads();
  int ex = wpre[w] + xv - v;
  offs[t] = ex;
  starts[t] = ex;
  __syncthreads();
  for (int i = t; i < tot; i += 256) {
    unsigned e = cb_base[i];
    int pos = atomicAdd(&offs[(e >> 17) & 255], 1);
    csr[cb * CAPC + pos] = e;  // scatter within 18KB window: L2-absorbed
  }
  int n = cb * NPB + t;
  if (n < NN) {
    ns[n] = cb * CAPC + starts[t];
    deg[n] = hist[t];
  }
}

// ===== k_af: register-gather aggregate + fused final MFMA (16 nodes/block) ===
__launch_bounds__(128)
__global__ void k_af(const unsigned* __restrict__ csr, const int* __restrict__ ns,
                     const int* __restrict__ deg, const uint2* __restrict__ P2,
                     const uint2* __restrict__ Q2, const float* __restrict__ x,
                     const ushort* __restrict__ WfT, const float* __restrict__ b2,
                     const float* __restrict__ bs, float* __restrict__ out) {
  __shared__ ushort ubf[16 * 72];
  __shared__ ushort xbf[16 * 72];
  __shared__ float dsc[16];
  int t = threadIdx.x;
  int n0 = blockIdx.x * 16;
  int w = t >> 6, lane = t & 63;
  int eg = lane >> 4, c = lane & 15;
  // preload x tile into regs (hides under gather)
  float4 xr[2];
  #pragma unroll
  for (int i = 0; i < 2; ++i) {
    int idx = t + i * 128;
    int r = idx >> 4, cc = idx & 15;
    xr[i] = reinterpret_cast<const float4*>(x)[(n0 + r) * 16 + cc];
  }
  if (t < 16) dsc[t] = (deg[n0 + t] > 0) ? 1.f : 0.f;
  // phase A: gather-aggregate, 8 nodes per wave
  for (int k = 0; k < 8; ++k) {
    int n = n0 + w * 8 + k;
    int dg = deg[n], st = ns[n];
    uint2 q = Q2[n * 16 + c];
    float q0 = uplo(q.x), q1 = uphi(q.x), q2 = uplo(q.y), q3 = uphi(q.y);
    float a0 = 0.f, a1 = 0.f, a2 = 0.f, a3 = 0.f;
    int e = eg;
    while (e + 4 < dg) {
      unsigned s0 = csr[st + e] & 0x1FFFFu;
      unsigned s1 = csr[st + e + 4] & 0x1FFFFu;
      uint2 p0 = P2[s0 * 16 + c];
      uint2 p1 = P2[s1 * 16 + c];
      a0 += fmaxf(uplo(p0.x) + q0, 0.f); a1 += fmaxf(uphi(p0.x) + q1, 0.f);
      a2 += fmaxf(uplo(p0.y) + q2, 0.f); a3 += fmaxf(uphi(p0.y) + q3, 0.f);
      a0 += fmaxf(uplo(p1.x) + q0, 0.f); a1 += fmaxf(uphi(p1.x) + q1, 0.f);
      a2 += fmaxf(uplo(p1.y) + q2, 0.f); a3 += fmaxf(uphi(p1.y) + q3, 0.f);
      e += 8;
    }
    if (e < dg) {
      unsigned s0 = csr[st + e] & 0x1FFFFu;
      uint2 p0 = P2[s0 * 16 + c];
      a0 += fmaxf(uplo(p0.x) + q0, 0.f); a1 += fmaxf(uphi(p0.x) + q1, 0.f);
      a2 += fmaxf(uplo(p0.y) + q2, 0.f); a3 += fmaxf(uphi(p0.y) + q3, 0.f);
    }
    a0 += __shfl_xor(a0, 16); a0 += __shfl_xor(a0, 32);
    a1 += __shfl_xor(a1, 16); a1 += __shfl_xor(a1, 32);
    a2 += __shfl_xor(a2, 16); a2 += __shfl_xor(a2, 32);
    a3 += __shfl_xor(a3, 16); a3 += __shfl_xor(a3, 32);
    if (eg == 0) {
      float inv = 1.f / (float)max(dg, 1);
      *reinterpret_cast<uint2*>(&ubf[(w * 8 + k) * 72 + c * 4]) =
          make_uint2(pk2(a0 * inv, a1 * inv), pk2(a2 * inv, a3 * inv));
    }
  }
  // write x tile bf16
  #pragma unroll
  for (int i = 0; i < 2; ++i) {
    int idx = t + i * 128;
    int r = idx >> 4, cc = idx & 15;
    *reinterpret_cast<uint2*>(&xbf[r * 72 + cc * 4]) =
        make_uint2(pk2(xr[i].x, xr[i].y), pk2(xr[i].z, xr[i].w));
  }
  __syncthreads();
  // phase B: out[16x64] = [u,x] @ WfT^T + bs (+ b2*dsc); wave w -> cols w*32..+31
  int li = lane & 15, lg = lane >> 4;
  f32x4 acc[2];
  acc[0] = (f32x4){0.f, 0.f, 0.f, 0.f};
  acc[1] = (f32x4){0.f, 0.f, 0.f, 0.f};
  #pragma unroll
  for (int s = 0; s < 4; ++s) {
    const ushort* src = (s < 2) ? ubf : xbf;
    bf16x8 a = *reinterpret_cast<const bf16x8*>(&src[li * 72 + (s & 1) * 32 + lg * 8]);
    #pragma unroll
    for (int n = 0; n < 2; ++n) {
      int ct = w * 2 + n;
      bf16x8 b = *reinterpret_cast<const bf16x8*>(&WfT[(ct * 16 + li) * 128 + s * 32 + lg * 8]);
      acc[n] = __builtin_amdgcn_mfma_f32_16x16x32_bf16(a, b, acc[n], 0, 0, 0);
    }
  }
  #pragma unroll
  for (int n = 0; n < 2; ++n) {
    int col = (w * 2 + n) * 16 + li;
    float bsv = bs[col], b2v = b2[col];
    #pragma unroll
    for (int q = 0; q < 4; ++q) {
      int rl = lg * 4 + q;
      out[(n0 + rl) * 64 + col] = acc[n][q] + bsv + dsc[rl] * b2v;
    }
  }
}

extern "C" void kernel_launch(void* const* d_in, const int* in_sizes, int n_in,
                              void* d_out, int out_size, void* d_ws, size_t ws_size,
                              hipStream_t stream) {
  const float* x   = (const float*)d_in[0];
  const int*   ei  = (const int*)d_in[1];
  const float* w1  = (const float*)d_in[2];
  const float* b1  = (const float*)d_in[3];
  const float* w2  = (const float*)d_in[4];
  const float* b2  = (const float*)d_in[5];
  const float* wsw = (const float*)d_in[6];
  const float* bs  = (const float*)d_in[7];
  float* out = (float*)d_out;
  char* ws = (char*)d_ws;
  int* ccnt      = (int*)(ws + OFF_CCNT);
  int* deg       = (int*)(ws + OFF_DEG);
  int* ns        = (int*)(ws + OFF_NS);
  unsigned* cbuf = (unsigned*)(ws + OFF_CBUF);
  unsigned* csr  = (unsigned*)(ws + OFF_CSR);
  ushort* P      = (ushort*)(ws + OFF_P);
  ushort* Qb     = (ushort*)(ws + OFF_Q);
  ushort* WfT    = (ushort*)(ws + OFF_WFT);

  hipMemsetAsync(ccnt, 0, NBC * sizeof(int), stream);
  k_pre<<<NBLA + NLI1 + 1, 512, 0, stream>>>(ei, ccnt, cbuf, x, w1, b1, w2, wsw,
                                             P, Qb, WfT);
  k_csr<<<NBC, 256, 0, stream>>>(ccnt, cbuf, csr, ns, deg);
  k_af<<<NAF, 128, 0, stream>>>(csr, ns, deg, (const uint2*)P, (const uint2*)Qb,
                                x, WfT, b2, bs, out);
}